// Round 1
// baseline (1692.486 us; speedup 1.0000x reference)
//
#include <hip/hip_runtime.h>

#define FP8_MAX_V 448.0f
#define M_DIM 16384
#define N_DIM 4096
#define K_DIM 4096

typedef float f32x4 __attribute__((ext_vector_type(4)));

// ---- fp8 pack helper: 4 fp32 -> 4 fp8 e4m3fn bytes (HW RNE conversion) ----
__device__ inline unsigned pack4_fp8(float4 v, float s) {
    float a = fminf(fmaxf(v.x * s, -FP8_MAX_V), FP8_MAX_V);
    float b = fminf(fmaxf(v.y * s, -FP8_MAX_V), FP8_MAX_V);
    float c = fminf(fmaxf(v.z * s, -FP8_MAX_V), FP8_MAX_V);
    float d = fminf(fmaxf(v.w * s, -FP8_MAX_V), FP8_MAX_V);
    int p = __builtin_amdgcn_cvt_pk_fp8_f32(a, b, 0, false);   // bytes 0,1
    p = __builtin_amdgcn_cvt_pk_fp8_f32(c, d, p, true);        // bytes 2,3
    return (unsigned)p;
}

// ---- async 16B global -> LDS (wave-uniform LDS base + lane*16) ----
__device__ inline void lds_cp16(const unsigned char* g, unsigned char* l) {
    __builtin_amdgcn_global_load_lds(
        (const __attribute__((address_space(1))) unsigned int*)g,
        (__attribute__((address_space(3))) unsigned int*)l,
        16, 0, 0);
}

__global__ void init_scales_kernel(unsigned* s) {
    s[0] = 0u;
    s[1] = 0u;
}

__global__ void amax_kernel(const float4* __restrict__ p, unsigned n4,
                            unsigned* __restrict__ out) {
    unsigned i = blockIdx.x * blockDim.x + threadIdx.x;
    unsigned stride = gridDim.x * blockDim.x;
    float m = 0.f;
    for (; i < n4; i += stride) {
        float4 v = p[i];
        m = fmaxf(m, fmaxf(fmaxf(fabsf(v.x), fabsf(v.y)),
                           fmaxf(fabsf(v.z), fabsf(v.w))));
    }
    // wave-64 reduce
    for (int off = 32; off > 0; off >>= 1)
        m = fmaxf(m, __shfl_down(m, off, 64));
    __shared__ float smax[4];
    int w = threadIdx.x >> 6, lane = threadIdx.x & 63;
    if (lane == 0) smax[w] = m;
    __syncthreads();
    if (threadIdx.x == 0) {
        m = fmaxf(fmaxf(smax[0], smax[1]), fmaxf(smax[2], smax[3]));
        atomicMax(out, __float_as_uint(m));   // valid: amax >= 0
    }
}

// x [M,K] fp32 -> x_fp8 [M,K]; one float4 -> one packed uint per thread
__global__ void quant_x_kernel(const float4* __restrict__ x,
                               unsigned* __restrict__ xq,
                               const unsigned* __restrict__ ab) {
    float scale = FP8_MAX_V / fmaxf(__uint_as_float(ab[0]), 1e-12f);
    unsigned gid = blockIdx.x * blockDim.x + threadIdx.x;
    xq[gid] = pack4_fp8(x[gid], scale);
}

// weight [K,N] fp32 -> w_fp8 [N,K] (quantized transpose) via 64x64 LDS tile
__global__ void quant_w_t_kernel(const float* __restrict__ w,
                                 unsigned char* __restrict__ wq,
                                 const unsigned* __restrict__ ab) {
    __shared__ unsigned char tile[64][65];   // [n_local][k_local], +1 pad
    float scale = FP8_MAX_V / fmaxf(__uint_as_float(ab[0]), 1e-12f);
    int t = threadIdx.x;
    int k0 = blockIdx.y << 6, n0 = blockIdx.x << 6;
    int kr = t >> 4;           // 0..15
    int nc = (t & 15) << 2;    // 0,4,..,60
#pragma unroll
    for (int ph = 0; ph < 4; ++ph) {
        int k = kr + (ph << 4);
        float4 v = *(const float4*)(w + (size_t)(k0 + k) * N_DIM + n0 + nc);
        unsigned p = pack4_fp8(v, scale);
        tile[nc + 0][k] = (unsigned char)(p & 0xff);
        tile[nc + 1][k] = (unsigned char)((p >> 8) & 0xff);
        tile[nc + 2][k] = (unsigned char)((p >> 16) & 0xff);
        tile[nc + 3][k] = (unsigned char)(p >> 24);
    }
    __syncthreads();
    int nl = t >> 2, ks = (t & 3) << 4;
    unsigned o[4];
#pragma unroll
    for (int q = 0; q < 4; ++q) {
        int kb = ks + q * 4;
        o[q] = (unsigned)tile[nl][kb] | ((unsigned)tile[nl][kb + 1] << 8) |
               ((unsigned)tile[nl][kb + 2] << 16) |
               ((unsigned)tile[nl][kb + 3] << 24);
    }
    uint4 ov = make_uint4(o[0], o[1], o[2], o[3]);
    *(uint4*)(wq + (size_t)(n0 + nl) * K_DIM + k0 + ks) = ov;
}

// ---- fp8 GEMM, m97/m145 structure: 128x128 tile, BK=64, 256 threads ----
// A = x_fp8 [M,K], Bt = w_fp8 [N,K], C = out [M,N] fp32
__global__ __launch_bounds__(256) void gemm_fp8_kernel(
    const unsigned char* __restrict__ A,
    const unsigned char* __restrict__ Bt,
    float* __restrict__ C,
    const unsigned* __restrict__ ab) {
    __shared__ __align__(16) unsigned char As[128 * 64];  // 8 KB, row-major [m][k]
    __shared__ __align__(16) unsigned char Bs[128 * 64];  // 8 KB, row-major [n][k]

    const int t = threadIdx.x;
    const int w = t >> 6;        // wave 0..3
    const int ln = t & 63;
    const int wi = w >> 1;       // wave row (0..1) -> 64 rows
    const int wj = w & 1;        // wave col (0..1) -> 64 cols
    const int lrow = ln & 15;
    const int lgrp = ln >> 4;    // 0..3

    const int m0 = blockIdx.y * 128;
    const int n0 = blockIdx.x * 128;

    f32x4 acc[4][4] = {};

    const unsigned char* Ag = A + (size_t)m0 * K_DIM;
    const unsigned char* Bg = Bt + (size_t)n0 * K_DIM;

    // staging geometry: inst i, flat = i*4096 + w*1024 + ln*16
    const int flat0 = w * 1024 + ln * 16;
    const int row0 = flat0 >> 6, col0 = flat0 & 63;
    const int flat1 = 4096 + flat0;
    const int row1 = flat1 >> 6, col1 = flat1 & 63;

    for (int kt = 0; kt < K_DIM; kt += 64) {
        lds_cp16(Ag + (size_t)row0 * K_DIM + kt + col0, As + w * 1024);
        lds_cp16(Ag + (size_t)row1 * K_DIM + kt + col1, As + 4096 + w * 1024);
        lds_cp16(Bg + (size_t)row0 * K_DIM + kt + col0, Bs + w * 1024);
        lds_cp16(Bg + (size_t)row1 * K_DIM + kt + col1, Bs + 4096 + w * 1024);
        __syncthreads();   // compiler emits vmcnt(0) drain before barrier
#pragma unroll
        for (int kk = 0; kk < 64; kk += 32) {
            long af[4], bf[4];
#pragma unroll
            for (int i = 0; i < 4; ++i)
                af[i] = *(const long*)(As + (wi * 64 + i * 16 + lrow) * 64 + kk + lgrp * 8);
#pragma unroll
            for (int j = 0; j < 4; ++j)
                bf[j] = *(const long*)(Bs + (wj * 64 + j * 16 + lrow) * 64 + kk + lgrp * 8);
#pragma unroll
            for (int i = 0; i < 4; ++i)
#pragma unroll
                for (int j = 0; j < 4; ++j)
                    acc[i][j] = __builtin_amdgcn_mfma_f32_16x16x32_fp8_fp8(
                        af[i], bf[j], acc[i][j], 0, 0, 0);
        }
        __syncthreads();
    }

    // epilogue: out *= (1/x_scale) * (1/w_scale), computed exactly like ref
    float ax = fmaxf(__uint_as_float(ab[0]), 1e-12f);
    float aw = fmaxf(__uint_as_float(ab[1]), 1e-12f);
    float xs = FP8_MAX_V / ax;
    float wsc = FP8_MAX_V / aw;
    float oscale = (1.0f / xs) * (1.0f / wsc);

#pragma unroll
    for (int i = 0; i < 4; ++i) {
#pragma unroll
        for (int j = 0; j < 4; ++j) {
            int row = m0 + wi * 64 + i * 16 + lgrp * 4;
            int col = n0 + wj * 64 + j * 16 + lrow;
            float* cp = C + (size_t)row * N_DIM + col;
#pragma unroll
            for (int r = 0; r < 4; ++r)
                cp[(size_t)r * N_DIM] = acc[i][j][r] * oscale;
        }
    }
}

extern "C" void kernel_launch(void* const* d_in, const int* in_sizes, int n_in,
                              void* d_out, int out_size, void* d_ws, size_t ws_size,
                              hipStream_t stream) {
    const float* x = (const float*)d_in[0];    // [8,2048,4096] fp32
    const float* wt = (const float*)d_in[1];   // [4096,4096] fp32
    float* out = (float*)d_out;                // [16384,4096] fp32

    // ws layout: x_fp8 (64 MB) | w_fp8 (16 MB) | amax_x, amax_w (8 B)
    unsigned char* ws = (unsigned char*)d_ws;
    unsigned char* xq = ws;
    unsigned char* wq = ws + (size_t)M_DIM * K_DIM;
    unsigned* scales = (unsigned*)(ws + (size_t)M_DIM * K_DIM + (size_t)N_DIM * K_DIM);

    init_scales_kernel<<<1, 1, 0, stream>>>(scales);
    amax_kernel<<<2048, 256, 0, stream>>>(
        (const float4*)x, (unsigned)((size_t)M_DIM * K_DIM / 4), scales + 0);
    amax_kernel<<<1024, 256, 0, stream>>>(
        (const float4*)wt, (unsigned)((size_t)K_DIM * N_DIM / 4), scales + 1);
    quant_x_kernel<<<(unsigned)((size_t)M_DIM * K_DIM / 4 / 256), 256, 0, stream>>>(
        (const float4*)x, (unsigned*)xq, scales);
    quant_w_t_kernel<<<dim3(N_DIM / 64, K_DIM / 64), 256, 0, stream>>>(wt, wq, scales + 1);
    gemm_fp8_kernel<<<dim3(N_DIM / 128, M_DIM / 128), 256, 0, stream>>>(xq, wq, out, scales);
}

// Round 2
// 1042.430 us; speedup vs baseline: 1.6236x; 1.6236x over previous
//
#include <hip/hip_runtime.h>

#define FP8_MAX_V 448.0f
#define M_DIM 16384
#define N_DIM 4096
#define K_DIM 4096

// LDS row stride: 80 bytes = 5 x 16B chunks (4 data + 1 pad).
// 80 B = 20 banks -> row r starts at bank (20*r)%32, breaking the 8-way
// conflict of the 64 B stride (which gave bank = 16*(lrow&1)+2*lgrp).
#define LDS_STRIDE 80
#define LDS_TILE_BYTES (128 * LDS_STRIDE)   // 10240 = 10 x 1024B insts

typedef float f32x4 __attribute__((ext_vector_type(4)));

// ---- fp8 pack helper: 4 fp32 -> 4 fp8 e4m3fn bytes (HW RNE conversion) ----
__device__ inline unsigned pack4_fp8(float4 v, float s) {
    float a = fminf(fmaxf(v.x * s, -FP8_MAX_V), FP8_MAX_V);
    float b = fminf(fmaxf(v.y * s, -FP8_MAX_V), FP8_MAX_V);
    float c = fminf(fmaxf(v.z * s, -FP8_MAX_V), FP8_MAX_V);
    float d = fminf(fmaxf(v.w * s, -FP8_MAX_V), FP8_MAX_V);
    int p = __builtin_amdgcn_cvt_pk_fp8_f32(a, b, 0, false);   // bytes 0,1
    p = __builtin_amdgcn_cvt_pk_fp8_f32(c, d, p, true);        // bytes 2,3
    return (unsigned)p;
}

// ---- async 16B global -> LDS (wave-uniform LDS base + lane*16) ----
__device__ inline void lds_cp16(const unsigned char* g, unsigned char* l) {
    __builtin_amdgcn_global_load_lds(
        (const __attribute__((address_space(1))) unsigned int*)g,
        (__attribute__((address_space(3))) unsigned int*)l,
        16, 0, 0);
}

__global__ void init_scales_kernel(unsigned* s) {
    s[0] = 0u;
    s[1] = 0u;
}

__global__ void amax_kernel(const float4* __restrict__ p, unsigned n4,
                            unsigned* __restrict__ out) {
    unsigned i = blockIdx.x * blockDim.x + threadIdx.x;
    unsigned stride = gridDim.x * blockDim.x;
    float m = 0.f;
    for (; i < n4; i += stride) {
        float4 v = p[i];
        m = fmaxf(m, fmaxf(fmaxf(fabsf(v.x), fabsf(v.y)),
                           fmaxf(fabsf(v.z), fabsf(v.w))));
    }
    for (int off = 32; off > 0; off >>= 1)
        m = fmaxf(m, __shfl_down(m, off, 64));
    __shared__ float smax[4];
    int w = threadIdx.x >> 6, lane = threadIdx.x & 63;
    if (lane == 0) smax[w] = m;
    __syncthreads();
    if (threadIdx.x == 0) {
        m = fmaxf(fmaxf(smax[0], smax[1]), fmaxf(smax[2], smax[3]));
        atomicMax(out, __float_as_uint(m));   // valid: amax >= 0
    }
}

// x [M,K] fp32 -> x_fp8 [M,K]; one float4 -> one packed uint per thread
__global__ void quant_x_kernel(const float4* __restrict__ x,
                               unsigned* __restrict__ xq,
                               const unsigned* __restrict__ ab) {
    float scale = FP8_MAX_V / fmaxf(__uint_as_float(ab[0]), 1e-12f);
    unsigned gid = blockIdx.x * blockDim.x + threadIdx.x;
    xq[gid] = pack4_fp8(x[gid], scale);
}

// weight [K,N] fp32 -> w_fp8 [N,K] (quantized transpose) via 64x64 LDS tile
__global__ void quant_w_t_kernel(const float* __restrict__ w,
                                 unsigned char* __restrict__ wq,
                                 const unsigned* __restrict__ ab) {
    __shared__ unsigned char tile[64][65];   // [n_local][k_local], +1 pad
    float scale = FP8_MAX_V / fmaxf(__uint_as_float(ab[0]), 1e-12f);
    int t = threadIdx.x;
    int k0 = blockIdx.y << 6, n0 = blockIdx.x << 6;
    int kr = t >> 4;           // 0..15
    int nc = (t & 15) << 2;    // 0,4,..,60
#pragma unroll
    for (int ph = 0; ph < 4; ++ph) {
        int k = kr + (ph << 4);
        float4 v = *(const float4*)(w + (size_t)(k0 + k) * N_DIM + n0 + nc);
        unsigned p = pack4_fp8(v, scale);
        tile[nc + 0][k] = (unsigned char)(p & 0xff);
        tile[nc + 1][k] = (unsigned char)((p >> 8) & 0xff);
        tile[nc + 2][k] = (unsigned char)((p >> 16) & 0xff);
        tile[nc + 3][k] = (unsigned char)(p >> 24);
    }
    __syncthreads();
    int nl = t >> 2, ks = (t & 3) << 4;
    unsigned o[4];
#pragma unroll
    for (int q = 0; q < 4; ++q) {
        int kb = ks + q * 4;
        o[q] = (unsigned)tile[nl][kb] | ((unsigned)tile[nl][kb + 1] << 8) |
               ((unsigned)tile[nl][kb + 2] << 16) |
               ((unsigned)tile[nl][kb + 3] << 24);
    }
    uint4 ov = make_uint4(o[0], o[1], o[2], o[3]);
    *(uint4*)(wq + (size_t)(n0 + nl) * K_DIM + k0 + ks) = ov;
}

// ---- fp8 GEMM: 128x128 tile, BK=64, 256 threads, stride-80 swizzled LDS ----
// A = x_fp8 [M,K], Bt = w_fp8 [N,K], C = out [M,N] fp32
__global__ __launch_bounds__(256) void gemm_fp8_kernel(
    const unsigned char* __restrict__ A,
    const unsigned char* __restrict__ Bt,
    float* __restrict__ C,
    const unsigned* __restrict__ ab) {
    __shared__ __align__(16) unsigned char As[LDS_TILE_BYTES];  // 10 KB
    __shared__ __align__(16) unsigned char Bs[LDS_TILE_BYTES];  // 10 KB

    const int t = threadIdx.x;
    const int w = t >> 6;        // wave 0..3
    const int ln = t & 63;
    const int wi = w >> 1;       // wave row (0..1) -> 64 rows
    const int wj = w & 1;        // wave col (0..1) -> 64 cols
    const int lrow = ln & 15;
    const int lgrp = ln >> 4;    // 0..3

    const int m0 = blockIdx.y * 128;
    const int n0 = blockIdx.x * 128;

    const unsigned char* Ag = A + (size_t)m0 * K_DIM;
    const unsigned char* Bg = Bt + (size_t)n0 * K_DIM;

    // Staging: 20 slots of 1024B (10 A, 10 B); wave w handles slots w+4u.
    // Within a slot, lane ln's 16B LDS chunk (phys chunk = slot*64+ln) maps
    // to row = chunk/5, col16 = chunk%5; col16==4 is pad (load dup of col16=3).
    const unsigned char* gsrc[5];
    unsigned char* ldst[5];
#pragma unroll
    for (int u = 0; u < 5; ++u) {
        int s = w + u * 4;                 // 0..19
        int is_b = (s >= 10);
        int si = is_b ? s - 10 : s;        // 0..9
        int chunk = si * 64 + ln;
        int row = chunk / 5;
        int c = chunk - row * 5;
        int gc = (c < 4) ? c : 3;          // pad lane: duplicate a valid fetch
        gsrc[u] = (is_b ? Bg : Ag) + (size_t)row * K_DIM + gc * 16;
        ldst[u] = (is_b ? Bs : As) + si * 1024;   // wave-uniform
    }

    f32x4 acc[4][4] = {};

    for (int kt = 0; kt < K_DIM; kt += 64) {
#pragma unroll
        for (int u = 0; u < 5; ++u)
            lds_cp16(gsrc[u] + kt, ldst[u]);
        __syncthreads();
#pragma unroll
        for (int kk = 0; kk < 64; kk += 32) {
            long af[4], bf[4];
#pragma unroll
            for (int i = 0; i < 4; ++i)
                af[i] = *(const long*)(As + (wi * 64 + i * 16 + lrow) * LDS_STRIDE + kk + lgrp * 8);
#pragma unroll
            for (int j = 0; j < 4; ++j)
                bf[j] = *(const long*)(Bs + (wj * 64 + j * 16 + lrow) * LDS_STRIDE + kk + lgrp * 8);
#pragma unroll
            for (int i = 0; i < 4; ++i)
#pragma unroll
                for (int j = 0; j < 4; ++j)
                    acc[i][j] = __builtin_amdgcn_mfma_f32_16x16x32_fp8_fp8(
                        af[i], bf[j], acc[i][j], 0, 0, 0);
        }
        __syncthreads();
    }

    // epilogue: out *= (1/x_scale) * (1/w_scale), computed exactly like ref
    float ax = fmaxf(__uint_as_float(ab[0]), 1e-12f);
    float aw = fmaxf(__uint_as_float(ab[1]), 1e-12f);
    float xs = FP8_MAX_V / ax;
    float wsc = FP8_MAX_V / aw;
    float oscale = (1.0f / xs) * (1.0f / wsc);

#pragma unroll
    for (int i = 0; i < 4; ++i) {
#pragma unroll
        for (int j = 0; j < 4; ++j) {
            int row = m0 + wi * 64 + i * 16 + lgrp * 4;
            int col = n0 + wj * 64 + j * 16 + lrow;
            float* cp = C + (size_t)row * N_DIM + col;
#pragma unroll
            for (int r = 0; r < 4; ++r)
                cp[(size_t)r * N_DIM] = acc[i][j][r] * oscale;
        }
    }
}

extern "C" void kernel_launch(void* const* d_in, const int* in_sizes, int n_in,
                              void* d_out, int out_size, void* d_ws, size_t ws_size,
                              hipStream_t stream) {
    const float* x = (const float*)d_in[0];    // [8,2048,4096] fp32
    const float* wt = (const float*)d_in[1];   // [4096,4096] fp32
    float* out = (float*)d_out;                // [16384,4096] fp32

    // ws layout: x_fp8 (64 MB) | w_fp8 (16 MB) | amax_x, amax_w (8 B)
    unsigned char* ws = (unsigned char*)d_ws;
    unsigned char* xq = ws;
    unsigned char* wq = ws + (size_t)M_DIM * K_DIM;
    unsigned* scales = (unsigned*)(ws + (size_t)M_DIM * K_DIM + (size_t)N_DIM * K_DIM);

    init_scales_kernel<<<1, 1, 0, stream>>>(scales);
    amax_kernel<<<2048, 256, 0, stream>>>(
        (const float4*)x, (unsigned)((size_t)M_DIM * K_DIM / 4), scales + 0);
    amax_kernel<<<1024, 256, 0, stream>>>(
        (const float4*)wt, (unsigned)((size_t)K_DIM * N_DIM / 4), scales + 1);
    quant_x_kernel<<<(unsigned)((size_t)M_DIM * K_DIM / 4 / 256), 256, 0, stream>>>(
        (const float4*)x, (unsigned*)xq, scales);
    quant_w_t_kernel<<<dim3(N_DIM / 64, K_DIM / 64), 256, 0, stream>>>(wt, wq, scales + 1);
    gemm_fp8_kernel<<<dim3(N_DIM / 128, M_DIM / 128), 256, 0, stream>>>(xq, wq, out, scales);
}